// Round 1
// baseline (642.566 us; speedup 1.0000x reference)
//
#include <hip/hip_runtime.h>
#include <hip/hip_bf16.h>

// NeuralODE RK4, bf16 MFMA persistent kernel, swapped-operand layout,
// ROLE-SPLIT waves to halve LDS broadcast-read traffic.
//
// BS=1024, ZDIM=HID=256, TLEN=128 -> 127 steps x 4 stages = 508 f-evals.
//
// 64 WGs x 512 threads (8 waves, 2/SIMD). WG owns 16 batch rows.
//   waves 0-3 (grp=0): hold W1 frags, compute S = z@W1, tanh -> hbuf
//   waves 4-7 (grp=1): hold W2 frags, compute f = h@W2, RK4 update -> zbuf
// Each wave owns 64 output cols (4 n-tiles). The state B-frag a wave reads
// is independent of its column count, so 4 readers/GEMM instead of 8 halves
// LDS read instructions (the measured bottleneck: 128 ds_read_b128/stage
// ~1536 cyc of ~2518 cyc/stage).
//
// Swapped trick: S^T = W^T @ z^T (weights as MFMA A-operand). C/D layout:
// col(lane&15) = batch row m, row(q*4+r) = output col c. LDS round-trip is
// per-m contiguous: packed b64 writes, b128 frag reads, row stride 264 u16.

#define BS   1024
#define ZDIM 256
#define TLEN 128
#define ROWSTRIDE 264   // u16 units; 528 B = 16B-aligned, odd multiple of 4 units

typedef short v8s __attribute__((ext_vector_type(8)));
typedef float v4f __attribute__((ext_vector_type(4)));

static __device__ __forceinline__ ushort f2bf_rne(float x) {
    union { float f; unsigned u; } v; v.f = x;
    unsigned r = v.u + 0x7FFFu + ((v.u >> 16) & 1u);
    return (ushort)(r >> 16);
}

static __device__ __forceinline__ unsigned pk2(float a, float b) {
    union { __hip_bfloat162 h; unsigned u; } cv;
    cv.h = __float22bfloat162_rn(make_float2(a, b));
    return cv.u;
}

static __device__ __forceinline__ float fast_tanh(float x) {
    // tanh(x) = 1 - 2/(exp2(2x*log2e)+1); v_exp + v_rcp, no slow libm div
    float e = __builtin_amdgcn_exp2f(2.88539008177793f * x);
    float r = __builtin_amdgcn_rcpf(e + 1.0f);
    return 1.0f - 2.0f * r;
}

__global__ __launch_bounds__(512, 2)
void ode_mfma_kernel(const float* __restrict__ z0,
                     const float* __restrict__ t,
                     const float* __restrict__ W1,
                     const float* __restrict__ b1,
                     const float* __restrict__ W2,
                     const float* __restrict__ b2,
                     float* __restrict__ out)
{
    // state buffers, swapped layout: buf[m][c] bf16, row stride ROWSTRIDE
    __shared__ ushort zbuf[16 * ROWSTRIDE];
    __shared__ ushort hbuf[16 * ROWSTRIDE];
    __shared__ float  hsh[TLEN];            // per-step h = t[s+1]-t[s]

    const int tid  = threadIdx.x;
    const int wv   = tid >> 6;        // 0..7
    const int lane = tid & 63;
    const int q    = lane >> 4;       // 0..3
    const int ln   = lane & 15;       // = batch row m (within tile)
    const int grp  = wv >> 2;         // 0: GEMM1+tanh waves, 1: GEMM2+RK4 waves
    const int wq   = wv & 3;          // column quad: cols [64*wq, 64*wq+64)
    const int rowbase = blockIdx.x * 16;

    if (tid < TLEN - 1) hsh[tid] = t[tid + 1] - t[tid];

    // ---- one-time: this group's weight matrix -> registers, A-frag layout ----
    // frag[ct][ks]: lane holds W[k = 32ks + 8q + j][c = 64wq + 16ct + ln]
    const float* __restrict__ Wsel = grp ? W2 : W1;
    const float* __restrict__ bsel = grp ? b2 : b1;

    v8s wf[4][8];
    #pragma unroll
    for (int ct = 0; ct < 4; ++ct) {
        const int c = wq * 64 + ct * 16 + ln;
        #pragma unroll
        for (int ks = 0; ks < 8; ++ks) {
            v8s a;
            #pragma unroll
            for (int j = 0; j < 8; ++j) {
                const int k = ks * 32 + q * 8 + j;
                a[j] = (short)f2bf_rne(Wsel[k * ZDIM + c]);
            }
            wf[ct][ks] = a;
        }
    }

    // biases in C'-layout: value row (c = 64wq + 16ct + 4q + r)
    v4f bf[4];
    #pragma unroll
    for (int ct = 0; ct < 4; ++ct)
        #pragma unroll
        for (int r = 0; r < 4; ++r)
            bf[ct][r] = bsel[wq * 64 + ct * 16 + q * 4 + r];

    // LDS offsets (u16 units)
    const int rdbase = ln * ROWSTRIDE + q * 8;            // + 32*ks, b128 reads
    const int wrbase = ln * ROWSTRIDE + wq * 64 + q * 4;  // + 16*ct,  b64 writes

    // ---- initial state (grp 1 owns the state) ----
    float zloc[4][4];   // z[m=ln][c = 64wq+16ct+4q+r], fp32
    float kacc[4][4];
    if (grp) {
        #pragma unroll
        for (int ct = 0; ct < 4; ++ct) {
            #pragma unroll
            for (int r = 0; r < 4; ++r)
                zloc[ct][r] = z0[(rowbase + ln) * ZDIM + wq * 64 + ct * 16 + q * 4 + r];
            uint2 p; p.x = pk2(zloc[ct][0], zloc[ct][1]); p.y = pk2(zloc[ct][2], zloc[ct][3]);
            *(uint2*)&zbuf[wrbase + ct * 16] = p;
        }
    }
    __syncthreads();

    #pragma unroll 1
    for (int step = 0; step < TLEN - 1; ++step) {
        const float h = hsh[step];

        #pragma unroll
        for (int stage = 0; stage < 4; ++stage) {
            // ---- phase A (waves 0-3): S^T = W1^T z^T + b1, tanh -> hbuf ----
            if (!grp) {
                v4f a0 = bf[0], a1 = bf[1], a2 = bf[2], a3 = bf[3];
                #pragma unroll
                for (int ks = 0; ks < 8; ++ks) {
                    const v8s zf = *(const v8s*)&zbuf[rdbase + ks * 32];
                    a0 = __builtin_amdgcn_mfma_f32_16x16x32_bf16(wf[0][ks], zf, a0, 0, 0, 0);
                    a1 = __builtin_amdgcn_mfma_f32_16x16x32_bf16(wf[1][ks], zf, a1, 0, 0, 0);
                    a2 = __builtin_amdgcn_mfma_f32_16x16x32_bf16(wf[2][ks], zf, a2, 0, 0, 0);
                    a3 = __builtin_amdgcn_mfma_f32_16x16x32_bf16(wf[3][ks], zf, a3, 0, 0, 0);
                }
                uint2 p0, p1, p2, p3;
                p0.x = pk2(fast_tanh(a0[0]), fast_tanh(a0[1]));
                p0.y = pk2(fast_tanh(a0[2]), fast_tanh(a0[3]));
                p1.x = pk2(fast_tanh(a1[0]), fast_tanh(a1[1]));
                p1.y = pk2(fast_tanh(a1[2]), fast_tanh(a1[3]));
                p2.x = pk2(fast_tanh(a2[0]), fast_tanh(a2[1]));
                p2.y = pk2(fast_tanh(a2[2]), fast_tanh(a2[3]));
                p3.x = pk2(fast_tanh(a3[0]), fast_tanh(a3[1]));
                p3.y = pk2(fast_tanh(a3[2]), fast_tanh(a3[3]));
                *(uint2*)&hbuf[wrbase]      = p0;
                *(uint2*)&hbuf[wrbase + 16] = p1;
                *(uint2*)&hbuf[wrbase + 32] = p2;
                *(uint2*)&hbuf[wrbase + 48] = p3;
            }
            __syncthreads();

            // ---- phase B (waves 4-7): f^T = W2^T h^T + b2, RK4 -> zbuf ----
            if (grp) {
                v4f f0 = bf[0], f1 = bf[1], f2 = bf[2], f3 = bf[3];
                #pragma unroll
                for (int ks = 0; ks < 8; ++ks) {
                    const v8s hf = *(const v8s*)&hbuf[rdbase + ks * 32];
                    f0 = __builtin_amdgcn_mfma_f32_16x16x32_bf16(wf[0][ks], hf, f0, 0, 0, 0);
                    f1 = __builtin_amdgcn_mfma_f32_16x16x32_bf16(wf[1][ks], hf, f1, 0, 0, 0);
                    f2 = __builtin_amdgcn_mfma_f32_16x16x32_bf16(wf[2][ks], hf, f2, 0, 0, 0);
                    f3 = __builtin_amdgcn_mfma_f32_16x16x32_bf16(wf[3][ks], hf, f3, 0, 0, 0);
                }
                v4f fa[4] = { f0, f1, f2, f3 };
                #pragma unroll
                for (int ct = 0; ct < 4; ++ct) {
                    float zn[4];
                    #pragma unroll
                    for (int r = 0; r < 4; ++r) {
                        const float f = fa[ct][r];
                        if (stage == 0) {
                            kacc[ct][r] = f;
                            zn[r] = zloc[ct][r] + 0.5f * h * f;
                        } else if (stage == 1) {
                            kacc[ct][r] += 2.0f * f;
                            zn[r] = zloc[ct][r] + 0.5f * h * f;
                        } else if (stage == 2) {
                            kacc[ct][r] += 2.0f * f;
                            zn[r] = zloc[ct][r] + h * f;
                        } else {
                            kacc[ct][r] += f;
                            zloc[ct][r] += (h * (1.0f / 6.0f)) * kacc[ct][r];
                            zn[r] = zloc[ct][r];
                        }
                    }
                    uint2 p; p.x = pk2(zn[0], zn[1]); p.y = pk2(zn[2], zn[3]);
                    *(uint2*)&zbuf[wrbase + ct * 16] = p;
                }
            }
            __syncthreads();
        }
    }

    // ---- final store (grp 1 owns the state) ----
    if (grp) {
        #pragma unroll
        for (int ct = 0; ct < 4; ++ct)
            #pragma unroll
            for (int r = 0; r < 4; ++r)
                out[(rowbase + ln) * ZDIM + wq * 64 + ct * 16 + q * 4 + r] = zloc[ct][r];
    }
}

extern "C" void kernel_launch(void* const* d_in, const int* in_sizes, int n_in,
                              void* d_out, int out_size, void* d_ws, size_t ws_size,
                              hipStream_t stream) {
    const float* z0 = (const float*)d_in[0];
    const float* t  = (const float*)d_in[1];
    const float* W1 = (const float*)d_in[2];
    const float* b1 = (const float*)d_in[3];
    const float* W2 = (const float*)d_in[4];
    const float* b2 = (const float*)d_in[5];
    float* out = (float*)d_out;

    dim3 grid(BS / 16);    // 64 workgroups, 16 batch rows each
    dim3 block(512);       // 8 waves: 4 GEMM1-waves + 4 GEMM2-waves
    hipLaunchKernelGGL(ode_mfma_kernel, grid, block, 0, stream,
                       z0, t, W1, b1, W2, b2, out);
}

// Round 2
// 621.575 us; speedup vs baseline: 1.0338x; 1.0338x over previous
//
#include <hip/hip_runtime.h>
#include <hip/hip_bf16.h>

// NeuralODE RK4, bf16 MFMA persistent kernel, swapped-operand layout.
// BS=1024, ZDIM=HID=256, TLEN=128 -> 127 steps x 4 stages = 508 f-evals.
//
// 64 WGs x 512 threads (8 waves, 2/SIMD). WG owns 16 batch rows; wave wv owns
// output cols [32wv, 32wv+32) for BOTH GEMMs (role-split measured WORSE:
// latency-bound, needs 2 active waves/SIMD). Weights in VGPRs, A-frag layout.
//
// Swapped trick: S^T = W^T @ z^T (weights as MFMA A-operand). C/D layout:
// col(lane&15) = batch row m, row(q*4+r) = output col c.
//
// LDS state buffers [m][c] bf16, row stride 264 u16, with a per-row 16B-unit
// swizzle unit' = (u&24)|((u-2*l3)&7) applied on BOTH write and read sides.
// Unswizzled, b64 writes were 4-way bank-conflicted (measured 1.25e7
// SQ_LDS_BANK_CONFLICT = ~384 cyc/stage); swizzled, writes are 2-way (free)
// and b128 reads stay conflict-free (start bank 4*((u-l3)%8), bijective in l3
// per 16-lane quarter).
//
// MFMA accumulation split into two 4-deep k-half chains per col-tile (4
// independent chains/wave, merged with v4f adds) to cut dep-chain latency.

#define BS   1024
#define ZDIM 256
#define TLEN 128
#define ROWSTRIDE 264   // u16 units; 528 B row, 32 data units of 16B + pad

typedef short v8s __attribute__((ext_vector_type(8)));
typedef float v4f __attribute__((ext_vector_type(4)));

static __device__ __forceinline__ ushort f2bf_rne(float x) {
    union { float f; unsigned u; } v; v.f = x;
    unsigned r = v.u + 0x7FFFu + ((v.u >> 16) & 1u);
    return (ushort)(r >> 16);
}

static __device__ __forceinline__ unsigned pk2(float a, float b) {
    union { __hip_bfloat162 h; unsigned u; } cv;
    cv.h = __float22bfloat162_rn(make_float2(a, b));
    return cv.u;
}

static __device__ __forceinline__ float fast_tanh(float x) {
    // tanh(x) = 1 - 2/(exp2(2x*log2e)+1); v_exp + v_rcp, no slow libm div
    float e = __builtin_amdgcn_exp2f(2.88539008177793f * x);
    float r = __builtin_amdgcn_rcpf(e + 1.0f);
    return 1.0f - 2.0f * r;
}

__global__ __launch_bounds__(512, 2)
void ode_mfma_kernel(const float* __restrict__ z0,
                     const float* __restrict__ t,
                     const float* __restrict__ W1,
                     const float* __restrict__ b1,
                     const float* __restrict__ W2,
                     const float* __restrict__ b2,
                     float* __restrict__ out)
{
    __shared__ ushort zbuf[16 * ROWSTRIDE];
    __shared__ ushort hbuf[16 * ROWSTRIDE];
    __shared__ float  hsh[TLEN];            // per-step h = t[s+1]-t[s]

    const int tid  = threadIdx.x;
    const int wv   = tid >> 6;        // 0..7
    const int lane = tid & 63;
    const int q    = lane >> 4;       // 0..3
    const int ln   = lane & 15;       // = batch row m (within tile)
    const int l3   = ln & 7;
    const int rowbase = blockIdx.x * 16;

    if (tid < TLEN - 1) hsh[tid] = t[tid + 1] - t[tid];

    // ---- one-time: weights -> registers, A-frag layout ----
    // frag[ct][ks]: lane holds W[k = 32ks + 8q + j][c = 32wv + 16ct + ln]
    v8s w1f[2][8], w2f[2][8];
    #pragma unroll
    for (int ct = 0; ct < 2; ++ct) {
        const int c = wv * 32 + ct * 16 + ln;
        #pragma unroll
        for (int ks = 0; ks < 8; ++ks) {
            v8s a, b;
            #pragma unroll
            for (int j = 0; j < 8; ++j) {
                const int k = ks * 32 + q * 8 + j;
                a[j] = (short)f2bf_rne(W1[k * ZDIM + c]);
                b[j] = (short)f2bf_rne(W2[k * ZDIM + c]);
            }
            w1f[ct][ks] = a;
            w2f[ct][ks] = b;
        }
    }

    // biases in C'-layout: value row (c = 32wv + 16ct + 4q + r)
    v4f b1f[2], b2f[2];
    #pragma unroll
    for (int ct = 0; ct < 2; ++ct)
        #pragma unroll
        for (int r = 0; r < 4; ++r) {
            b1f[ct][r] = b1[wv * 32 + ct * 16 + q * 4 + r];
            b2f[ct][r] = b2[wv * 32 + ct * 16 + q * 4 + r];
        }

    // ---- swizzled LDS addresses (u16 units) ----
    // unit'(u, ln) = (u & 24) | ((u - 2*l3) & 7); per-row bijective.
    int rdaddr[8];   // b128 reads: u_r = q + 4*ks
    #pragma unroll
    for (int ks = 0; ks < 8; ++ks) {
        const int u  = q + 4 * ks;
        const int up = (u & 24) | ((u - 2 * l3) & 7);
        rdaddr[ks] = ln * ROWSTRIDE + up * 8;
    }
    int wraddr[2];   // b64 writes: u_w = 4*wv + 2*ct + (q>>1), sub (q&1)*8B
    #pragma unroll
    for (int ct = 0; ct < 2; ++ct) {
        const int u  = 4 * wv + 2 * ct + (q >> 1);
        const int up = (u & 24) | ((u - 2 * l3) & 7);
        wraddr[ct] = ln * ROWSTRIDE + up * 8 + (q & 1) * 4;
    }

    // ---- initial state ----
    float zloc[2][4];   // z[m=ln][c = 32wv+16ct+4q+r], fp32
    #pragma unroll
    for (int ct = 0; ct < 2; ++ct) {
        #pragma unroll
        for (int r = 0; r < 4; ++r)
            zloc[ct][r] = z0[(rowbase + ln) * ZDIM + wv * 32 + ct * 16 + q * 4 + r];
        uint2 p; p.x = pk2(zloc[ct][0], zloc[ct][1]); p.y = pk2(zloc[ct][2], zloc[ct][3]);
        *(uint2*)&zbuf[wraddr[ct]] = p;
    }
    __syncthreads();

    float kacc[2][4];
    const v4f vz = { 0.f, 0.f, 0.f, 0.f };

    #pragma unroll 1
    for (int step = 0; step < TLEN - 1; ++step) {
        const float h = hsh[step];

        #pragma unroll
        for (int stage = 0; stage < 4; ++stage) {
            // ---- GEMM1: S^T = W1^T z^T + b1 (two 4-deep k-half chains) ----
            v4f a0A = b1f[0], a1A = b1f[1], a0B = vz, a1B = vz;
            #pragma unroll
            for (int ks = 0; ks < 4; ++ks) {
                const v8s zf = *(const v8s*)&zbuf[rdaddr[ks]];
                a0A = __builtin_amdgcn_mfma_f32_16x16x32_bf16(w1f[0][ks], zf, a0A, 0, 0, 0);
                a1A = __builtin_amdgcn_mfma_f32_16x16x32_bf16(w1f[1][ks], zf, a1A, 0, 0, 0);
            }
            #pragma unroll
            for (int ks = 4; ks < 8; ++ks) {
                const v8s zf = *(const v8s*)&zbuf[rdaddr[ks]];
                a0B = __builtin_amdgcn_mfma_f32_16x16x32_bf16(w1f[0][ks], zf, a0B, 0, 0, 0);
                a1B = __builtin_amdgcn_mfma_f32_16x16x32_bf16(w1f[1][ks], zf, a1B, 0, 0, 0);
            }
            const v4f acc0 = a0A + a0B;
            const v4f acc1 = a1A + a1B;

            // tanh -> hbuf (packed b64 per ct, swizzled)
            {
                uint2 p0, p1;
                p0.x = pk2(fast_tanh(acc0[0]), fast_tanh(acc0[1]));
                p0.y = pk2(fast_tanh(acc0[2]), fast_tanh(acc0[3]));
                p1.x = pk2(fast_tanh(acc1[0]), fast_tanh(acc1[1]));
                p1.y = pk2(fast_tanh(acc1[2]), fast_tanh(acc1[3]));
                *(uint2*)&hbuf[wraddr[0]] = p0;
                *(uint2*)&hbuf[wraddr[1]] = p1;
            }
            __syncthreads();

            // ---- GEMM2: f^T = W2^T h^T + b2 ----
            v4f f0A = b2f[0], f1A = b2f[1], f0B = vz, f1B = vz;
            #pragma unroll
            for (int ks = 0; ks < 4; ++ks) {
                const v8s hf = *(const v8s*)&hbuf[rdaddr[ks]];
                f0A = __builtin_amdgcn_mfma_f32_16x16x32_bf16(w2f[0][ks], hf, f0A, 0, 0, 0);
                f1A = __builtin_amdgcn_mfma_f32_16x16x32_bf16(w2f[1][ks], hf, f1A, 0, 0, 0);
            }
            #pragma unroll
            for (int ks = 4; ks < 8; ++ks) {
                const v8s hf = *(const v8s*)&hbuf[rdaddr[ks]];
                f0B = __builtin_amdgcn_mfma_f32_16x16x32_bf16(w2f[0][ks], hf, f0B, 0, 0, 0);
                f1B = __builtin_amdgcn_mfma_f32_16x16x32_bf16(w2f[1][ks], hf, f1B, 0, 0, 0);
            }
            const v4f fv0 = f0A + f0B;
            const v4f fv1 = f1A + f1B;

            // ---- RK4 epilogue ----
            #pragma unroll
            for (int ct = 0; ct < 2; ++ct) {
                float zn[4];
                #pragma unroll
                for (int r = 0; r < 4; ++r) {
                    const float f = (ct == 0) ? fv0[r] : fv1[r];
                    if (stage == 0) {
                        kacc[ct][r] = f;
                        zn[r] = zloc[ct][r] + 0.5f * h * f;
                    } else if (stage == 1) {
                        kacc[ct][r] += 2.0f * f;
                        zn[r] = zloc[ct][r] + 0.5f * h * f;
                    } else if (stage == 2) {
                        kacc[ct][r] += 2.0f * f;
                        zn[r] = zloc[ct][r] + h * f;
                    } else {
                        kacc[ct][r] += f;
                        zloc[ct][r] += (h * (1.0f / 6.0f)) * kacc[ct][r];
                        zn[r] = zloc[ct][r];
                    }
                }
                uint2 p; p.x = pk2(zn[0], zn[1]); p.y = pk2(zn[2], zn[3]);
                *(uint2*)&zbuf[wraddr[ct]] = p;
            }
            __syncthreads();
        }
    }

    // ---- final store (one-time, uncoalesced is fine) ----
    #pragma unroll
    for (int ct = 0; ct < 2; ++ct)
        #pragma unroll
        for (int r = 0; r < 4; ++r)
            out[(rowbase + ln) * ZDIM + wv * 32 + ct * 16 + q * 4 + r] = zloc[ct][r];
}

extern "C" void kernel_launch(void* const* d_in, const int* in_sizes, int n_in,
                              void* d_out, int out_size, void* d_ws, size_t ws_size,
                              hipStream_t stream) {
    const float* z0 = (const float*)d_in[0];
    const float* t  = (const float*)d_in[1];
    const float* W1 = (const float*)d_in[2];
    const float* b1 = (const float*)d_in[3];
    const float* W2 = (const float*)d_in[4];
    const float* b2 = (const float*)d_in[5];
    float* out = (float*)d_out;

    dim3 grid(BS / 16);    // 64 workgroups, 16 batch rows each
    dim3 block(512);       // 8 waves, 2 per SIMD
    hipLaunchKernelGGL(ode_mfma_kernel, grid, block, 0, stream,
                       z0, t, W1, b1, W2, b2, out);
}